// Round 3
// baseline (547.908 us; speedup 1.0000x reference)
//
#include <hip/hip_runtime.h>
#include <math.h>

// Problem constants (B=2, S=4096, D=4096, R=16, BOTTLE=64, SCALING=2)
#define BSROWS 8192     // B*S
#define DD 4096         // hidden
#define CATD 8192       // 2*D
#define NB 64           // bottleneck
#define NP1 160         // 32 (A_cat) + 64 (W1 base-half) + 64 (G1 base-half)
#define PS 164          // padded P stride (fp32) to break bank conflicts
#define HS 104          // padded Hcat stride (bf16)
#define KOUT 96         // 64 (h) + 32 (t)

typedef __attribute__((ext_vector_type(8))) short bf16x8;
typedef __attribute__((ext_vector_type(4))) float f32x4;

static __device__ __forceinline__ unsigned short f2bf(float f) {
  union { float f; unsigned u; } v; v.f = f;
  unsigned r = v.u + 0x7FFFu + ((v.u >> 16) & 1u);   // RNE
  return (unsigned short)(r >> 16);
}

static __device__ __forceinline__ bf16x8 pack8(const float* __restrict__ p) {
  float4 a = *(const float4*)p;
  float4 b = *(const float4*)(p + 4);
  bf16x8 r;
  r[0] = (short)f2bf(a.x); r[1] = (short)f2bf(a.y);
  r[2] = (short)f2bf(a.z); r[3] = (short)f2bf(a.w);
  r[4] = (short)f2bf(b.x); r[5] = (short)f2bf(b.y);
  r[6] = (short)f2bf(b.z); r[7] = (short)f2bf(b.w);
  return r;
}

// ---------------- prep 1: bf16 weight repack ----------------
// Wp1 [n=160][k=4096] n-major: n<16 A_pos, n<32 A_neg, n<96 W1 base-half, n<160 G1 base-half
// Wout [n=4096][k=96] n-major: k<64 W2[n][k], else 2*B_{pos,neg}[n][k-64]
__global__ void prep_weights(const float* __restrict__ A_pos, const float* __restrict__ A_neg,
                             const float* __restrict__ W1, const float* __restrict__ G1,
                             const float* __restrict__ W2, const float* __restrict__ B_pos,
                             const float* __restrict__ B_neg,
                             unsigned short* __restrict__ Wp1, unsigned short* __restrict__ Wout) {
  int tid = blockIdx.x * blockDim.x + threadIdx.x;
  const int total = NP1 * DD + DD * KOUT;
  for (int e = tid; e < total; e += gridDim.x * blockDim.x) {
    if (e < NP1 * DD) {
      int n = e >> 12, k = e & 4095;
      float v;
      if (n < 16)      v = A_pos[n * DD + k];
      else if (n < 32) v = A_neg[(n - 16) * DD + k];
      else if (n < 96) v = W1[(n - 32) * CATD + k];
      else             v = G1[(n - 96) * CATD + k];
      Wp1[e] = f2bf(v);
    } else {
      int e2 = e - NP1 * DD;
      int n = e2 / KOUT, j = e2 - n * KOUT;
      float v;
      if (j < NB) v = W2[n * NB + j];
      else {
        int i = j - NB;
        v = 2.f * ((i < 16) ? B_pos[n * 16 + i] : B_neg[n * 16 + (i - 16)]);
      }
      Wout[e2] = f2bf(v);
    }
  }
}

// ---------------- prep 2: M1/M2 = Bc @ {W1,G1}_lora-half^T ----------------
// partial[chunk][net][i][j], chunk = 512-wide K slice
__global__ void prep_m_partial(const float* __restrict__ B_pos, const float* __restrict__ B_neg,
                               const float* __restrict__ W1, const float* __restrict__ G1,
                               float* __restrict__ part) {
  int t = blockIdx.x * 256 + threadIdx.x;     // 32768 threads
  int chunk = t >> 12;
  int rem = t & 4095;
  int net = rem >> 11;
  int i = (rem >> 6) & 31;
  int j = rem & 63;
  const float* Bp = (i < 16) ? (B_pos + i) : (B_neg + (i - 16));
  const float* Wr = ((net == 0) ? W1 : G1) + (size_t)j * CATD + DD;
  float acc = 0.f;
  int d0 = chunk * 512;
#pragma unroll 8
  for (int d = 0; d < 512; ++d) acc += Bp[(size_t)(d0 + d) * 16] * Wr[d0 + d];
  part[t] = 2.f * acc;
}

__global__ void prep_m_reduce(const float* __restrict__ part,
                              float* __restrict__ M1, float* __restrict__ M2) {
  int t = blockIdx.x * 256 + threadIdx.x;     // 4096 threads
  int net = t >> 11;
  int ij = t & 2047;
  float s = 0.f;
#pragma unroll
  for (int c = 0; c < 8; ++c) s += part[c * 4096 + net * 2048 + ij];
  (net == 0 ? M1 : M2)[ij] = s;
}

// ---------------- main fused kernel ----------------
// 512 blocks x 512 threads, 16 rows/block, K(4096) split across two 4-wave groups.
__global__ __launch_bounds__(512, 4)
void fused_main(const float* __restrict__ x, const float* __restrict__ base,
                const unsigned short* __restrict__ Wp1, const unsigned short* __restrict__ Wout,
                const float* __restrict__ M1, const float* __restrict__ M2,
                const float* __restrict__ b1, const float* __restrict__ g1,
                const float* __restrict__ b2f, const float* __restrict__ G2,
                const float* __restrict__ g2, float* __restrict__ out) {
  __shared__ __align__(16) float P[2][16][PS];
  __shared__ __align__(16) unsigned short Hcat[16][HS];
  __shared__ float alpha_s[16];

  const int tid = threadIdx.x;
  const int w = tid >> 6;              // wave 0..7
  const int lane = tid & 63;
  const int col = lane & 15;           // MFMA A-row / B-col / C-col
  const int kseg = (lane >> 4) * 8;    // k sub-segment within 32
  const int kh = w >> 2;               // K half (0: k<2048, 1: k>=2048)
  const int wsub = w & 3;
  const long row0 = (long)blockIdx.x * 16;

  const float* xrow = x + (row0 + col) * DD;
  const float* brow = base + (row0 + col) * DD;

  // ---- phase 1: P[.,0:32]=x@A_cat^T, P[.,32:96]=base@W1b^T, P[.,96:160]=base@G1b^T
  f32x4 acc0 = {0.f, 0.f, 0.f, 0.f};
  f32x4 acc1 = {0.f, 0.f, 0.f, 0.f};
  f32x4 acc2 = {0.f, 0.f, 0.f, 0.f};
  const bool hasx = (wsub < 2);        // tiles {wsub, wsub+4, wsub+8}; tile<2 uses x
  const int kbeg = kh * 2048;
#pragma unroll 2
  for (int k0 = kbeg; k0 < kbeg + 2048; k0 += 32) {
    const int kk = k0 + kseg;
    bf16x8 ba = pack8(brow + kk);
    bf16x8 a0;
    if (hasx) a0 = pack8(xrow + kk); else a0 = ba;
    const unsigned short* wp = Wp1 + kk;
    bf16x8 bw0 = *(const bf16x8*)(wp + (size_t)(wsub * 16 + col) * DD);
    bf16x8 bw1 = *(const bf16x8*)(wp + (size_t)((wsub + 4) * 16 + col) * DD);
    acc0 = __builtin_amdgcn_mfma_f32_16x16x32_bf16(a0, bw0, acc0, 0, 0, 0);
    acc1 = __builtin_amdgcn_mfma_f32_16x16x32_bf16(ba, bw1, acc1, 0, 0, 0);
    if (hasx) {
      bf16x8 bw2 = *(const bf16x8*)(wp + (size_t)((wsub + 8) * 16 + col) * DD);
      acc2 = __builtin_amdgcn_mfma_f32_16x16x32_bf16(ba, bw2, acc2, 0, 0, 0);
    }
  }
  {
    const int rbase = (lane >> 4) * 4;
#pragma unroll
    for (int r = 0; r < 4; ++r) {
      P[kh][rbase + r][wsub * 16 + col] = acc0[r];
      P[kh][rbase + r][(wsub + 4) * 16 + col] = acc1[r];
      if (hasx) P[kh][rbase + r][(wsub + 8) * 16 + col] = acc2[r];
    }
  }
  __syncthreads();

  // ---- phase 2: h, hg, alpha; Hcat = alpha*[h ; t] (bf16)
  if (tid < 256) {
    const int row = tid >> 4, jg = tid & 15;
    float tl[32];
#pragma unroll
    for (int i = 0; i < 32; ++i) tl[i] = P[0][row][i] + P[1][row][i];
    float hv[4];
    float partg = 0.f;
#pragma unroll
    for (int jj = 0; jj < 4; ++jj) {
      const int j = jg * 4 + jj;
      float s1 = b1[j] + P[0][row][32 + j] + P[1][row][32 + j];
      float s2 = g1[j] + P[0][row][96 + j] + P[1][row][96 + j];
#pragma unroll
      for (int i = 0; i < 32; ++i) {
        s1 += tl[i] * M1[i * 64 + j];
        s2 += tl[i] * M2[i * 64 + j];
      }
      hv[jj] = fmaxf(s1, 0.f);
      partg += G2[j] * fmaxf(s2, 0.f);
    }
#pragma unroll
    for (int m = 8; m >= 1; m >>= 1) partg += __shfl_xor(partg, m);
    const float alpha = 1.f / (1.f + expf(-6.f * (partg + g2[0])));
    if (jg == 0) alpha_s[row] = alpha;
#pragma unroll
    for (int jj = 0; jj < 4; ++jj) Hcat[row][jg * 4 + jj] = f2bf(alpha * hv[jj]);
    if (jg < 8) {
#pragma unroll
      for (int ii = 0; ii < 4; ++ii)
        Hcat[row][64 + jg * 4 + ii] = f2bf(alpha * tl[jg * 4 + ii]);
    }
  }
  __syncthreads();

  // ---- phase 3: out = base + Hcat @ Wout + alpha*b2
  bf16x8 af0 = *(const bf16x8*)&Hcat[col][kseg];
  bf16x8 af1 = *(const bf16x8*)&Hcat[col][32 + kseg];
  bf16x8 af2 = *(const bf16x8*)&Hcat[col][64 + kseg];
  const int rbase = (lane >> 4) * 4;
  float al[4];
#pragma unroll
  for (int r = 0; r < 4; ++r) al[r] = alpha_s[rbase + r];

  for (int i = 0; i < 32; ++i) {
    const int nt = w + 8 * i;                 // 256 n-tiles / 8 waves
    const int gcol = nt * 16 + col;
    const unsigned short* wo = Wout + (size_t)gcol * KOUT;
    bf16x8 w0 = *(const bf16x8*)(wo + kseg);
    bf16x8 w1v = *(const bf16x8*)(wo + 32 + kseg);
    bf16x8 w2v = *(const bf16x8*)(wo + 64 + kseg);
    f32x4 c = {0.f, 0.f, 0.f, 0.f};
    c = __builtin_amdgcn_mfma_f32_16x16x32_bf16(af0, w0, c, 0, 0, 0);
    c = __builtin_amdgcn_mfma_f32_16x16x32_bf16(af1, w1v, c, 0, 0, 0);
    c = __builtin_amdgcn_mfma_f32_16x16x32_bf16(af2, w2v, c, 0, 0, 0);
    const float bb = b2f[gcol];
#pragma unroll
    for (int r = 0; r < 4; ++r) {
      const size_t off = (size_t)(row0 + rbase + r) * DD + gcol;
      out[off] = base[off] + c[r] + al[r] * bb;
    }
  }
}

extern "C" void kernel_launch(void* const* d_in, const int* in_sizes, int n_in,
                              void* d_out, int out_size, void* d_ws, size_t ws_size,
                              hipStream_t stream) {
  const float* x     = (const float*)d_in[0];
  const float* base  = (const float*)d_in[1];
  const float* A_pos = (const float*)d_in[2];
  const float* B_pos = (const float*)d_in[3];
  const float* A_neg = (const float*)d_in[4];
  const float* B_neg = (const float*)d_in[5];
  const float* W1    = (const float*)d_in[6];
  const float* b1    = (const float*)d_in[7];
  const float* W2    = (const float*)d_in[8];
  const float* b2    = (const float*)d_in[9];
  const float* G1    = (const float*)d_in[10];
  const float* g1    = (const float*)d_in[11];
  const float* G2    = (const float*)d_in[12];
  const float* g2    = (const float*)d_in[13];
  float* out = (float*)d_out;

  char* ws = (char*)d_ws;
  unsigned short* Wp1  = (unsigned short*)(ws);                 // 160*4096*2 = 1310720
  unsigned short* Wout = (unsigned short*)(ws + 1310720);       // 4096*96*2  =  786432
  float* M1   = (float*)(ws + 2097152);                         // 32*64*4 = 8192
  float* M2   = (float*)(ws + 2105344);                         // 8192
  float* part = (float*)(ws + 2113536);                         // 8*2*32*64*4 = 131072

  prep_weights<<<1024, 256, 0, stream>>>(A_pos, A_neg, W1, G1, W2, B_pos, B_neg, Wp1, Wout);
  prep_m_partial<<<128, 256, 0, stream>>>(B_pos, B_neg, W1, G1, part);
  prep_m_reduce<<<16, 256, 0, stream>>>(part, M1, M2);
  fused_main<<<512, 512, 0, stream>>>(x, base, Wp1, Wout, M1, M2, b1, g1, b2, G2, g2, out);
}